// Round 14
// baseline (1224.245 us; speedup 1.0000x reference)
//
#include <hip/hip_runtime.h>
#include <hip/hip_bf16.h>
#include <math.h>

#define BB 16
#define TT 360
#define VV 25
#define NN 9000
#define EE 72000
#define HH 128
#define RR (NN * BB)     // 144000 rows total
#define CROWS 18000      // rows per chunk (9000 nodes x 2 batches)
#define NPB 9000         // fused blocks (8 chunks x 1125), 16 rows each
#define NPART0 563       // partial-stats blocks for k_mm2 (L0)
#define NCLSS 12
#define EPSB 1e-5f

// chunked activation layout: row R(n,b) = (b>>1)*CROWS + n*2 + (b&1)

typedef _Float16 h4v __attribute__((ext_vector_type(4)));
typedef _Float16 h8v __attribute__((ext_vector_type(8)));
typedef float f4v __attribute__((ext_vector_type(4)));

__device__ __forceinline__ h8v cf8(unsigned packed) {
    uint4 cc = {packed, packed, packed, packed};
    return __builtin_bit_cast(h8v, cc);
}

// ---------------- graph preprocessing ----------------

__global__ void k_count(const int* __restrict__ ei, int* __restrict__ counts) {
    int e = blockIdx.x * 256 + threadIdx.x;
    if (e < EE) atomicAdd(&counts[ei[EE + e]], 1);
}

__global__ void k_dinv(const int* __restrict__ counts, float* __restrict__ dinv,
                       unsigned* __restrict__ d2p) {
    int n = blockIdx.x * 256 + threadIdx.x;
    if (n >= NN) return;
    float di = rsqrtf((float)(counts[n] + 1));
    dinv[n] = di;
    _Float16 d2 = (_Float16)(di * di);
    unsigned short u = __builtin_bit_cast(unsigned short, d2);
    d2p[n] = (unsigned)u | ((unsigned)u << 16);
}

// exclusive prefix over padded degrees deg4 = (deg+3)&~3
__global__ void k_scan(const int* __restrict__ counts, int* __restrict__ rowptr4) {
    __shared__ int part[1024];
    int t = threadIdx.x;
    int base = t * 9;
    int loc[9];
    int s = 0;
#pragma unroll
    for (int i = 0; i < 9; i++) {
        int idx = base + i;
        int v = (idx < NN) ? ((counts[idx] + 3) & ~3) : 0;
        loc[i] = s;
        s += v;
    }
    part[t] = s;
    __syncthreads();
    for (int d = 1; d < 1024; d <<= 1) {
        int v = (t >= d) ? part[t - d] : 0;
        __syncthreads();
        part[t] += v;
        __syncthreads();
    }
    int excl = (t == 0) ? 0 : part[t - 1];
#pragma unroll
    for (int i = 0; i < 9; i++) {
        int idx = base + i;
        if (idx < NN) rowptr4[idx] = excl + loc[i];
    }
    if (t == 1023) rowptr4[NN] = part[1023];
}

// csr entry: {src, coef packed as half2(cf,cf)}
__global__ void k_fill(const int* __restrict__ ei, const int* __restrict__ rowptr4,
                       int* __restrict__ cursor, const float* __restrict__ dinv,
                       int2* __restrict__ csr) {
    int e = blockIdx.x * 256 + threadIdx.x;
    if (e >= EE) return;
    int s = ei[e], d = ei[EE + e];
    int slot = rowptr4[d] + atomicAdd(&cursor[d], 1);
    _Float16 cfh = (_Float16)(dinv[s] * dinv[d]);
    unsigned short u = __builtin_bit_cast(unsigned short, cfh);
    int2 e2;
    e2.x = s;
    e2.y = (int)((unsigned)u | ((unsigned)u << 16));
    csr[slot] = e2;
}

// fill pad slots with {n, 0} (self row, zero coef)
__global__ void k_pad(const int* __restrict__ rowptr4, const int* __restrict__ cursor,
                      int2* __restrict__ csr) {
    int n = blockIdx.x * 256 + threadIdx.x;
    if (n >= NN) return;
    int beg = rowptr4[n] + cursor[n];
    int end = rowptr4[n + 1];
    int2 z;
    z.x = n;
    z.y = 0;
    for (int e = beg; e < end; e++) csr[e] = z;
}

// pre-convert the 11 layer weight matrices to f16 W^T images: Wh[l][c*128+k]
__global__ void k_wcvt(const float* __restrict__ sW, const float* __restrict__ mW,
                       const float* __restrict__ aW, _Float16* __restrict__ Wh) {
    int idx = blockIdx.x * 256 + threadIdx.x;
    if (idx >= 11 * 16384) return;
    int l = idx >> 14, r = idx & 16383;
    int k = r >> 7, c = r & 127;
    const float* src = (l < 2) ? sW + (size_t)l * 16384
                               : ((l == 2) ? mW : aW + (size_t)(l - 3) * 16384);
    Wh[(size_t)l * 16384 + c * 128 + k] = (_Float16)src[k * 128 + c];
}

// ---------------- L0 propagation of raw x (2 channels, f32) ----------------
__global__ void k_prop2(const float* __restrict__ x, float* __restrict__ P0,
                        const int* __restrict__ rowptr4, const int2* __restrict__ csr,
                        const float* __restrict__ dinv) {
    int n = blockIdx.x * 256 + threadIdx.x;
    if (n >= NN) return;
    int b = blockIdx.y;
    const float* xb = x + (size_t)b * NN * 2;
    float d2 = dinv[n] * dinv[n];
    float a0 = d2 * xb[2 * n], a1 = d2 * xb[2 * n + 1];
    int beg = rowptr4[n], end = rowptr4[n + 1];
    for (int j = beg; j < end; j++) {
        int2 e2 = csr[j];
        int s = e2.x;
        unsigned short u = (unsigned short)((unsigned)e2.y & 0xffffu);
        float cf = (float)__builtin_bit_cast(_Float16, u);
        a0 += cf * xb[2 * s];
        a1 += cf * xb[2 * s + 1];
    }
    float* Pb = P0 + (size_t)(n * BB + b) * 2;
    Pb[0] = a0;
    Pb[1] = a1;
}

// L0 matmul (K=2), writes chunked f16 layout, fused BN partial stats pS[c][part] (stride NPART0).
__global__ void __launch_bounds__(256) k_mm2(const float* __restrict__ P0,
                                             _Float16* __restrict__ A,
                                             const float* __restrict__ W,
                                             const float* __restrict__ bias,
                                             float* __restrict__ pS1, float* __restrict__ pS2) {
    __shared__ float L1[256][8], L2[256][8];
    int t = threadIdx.x;
    int cg = t & 15, c8 = cg * 8;
    float wv0[8], wv1[8], bv[8];
#pragma unroll
    for (int j = 0; j < 8; j++) {
        wv0[j] = W[c8 + j];
        wv1[j] = W[HH + c8 + j];
        bv[j] = bias[c8 + j];
    }
    float s1[8], s2[8];
#pragma unroll
    for (int j = 0; j < 8; j++) { s1[j] = 0.f; s2[j] = 0.f; }
    for (int idx = blockIdx.x * 256 + t; idx < RR * 16; idx += gridDim.x * 256) {
        int Rr = idx >> 4;
        int q = Rr / CROWS;
        int rr = Rr - q * CROWS;
        int n = rr >> 1;
        int b = q * 2 + (rr & 1);
        float p0 = P0[((size_t)n * BB + b) * 2], p1 = P0[((size_t)n * BB + b) * 2 + 1];
        h8v o;
#pragma unroll
        for (int j = 0; j < 8; j++) {
            float v = p0 * wv0[j] + p1 * wv1[j] + bv[j];
            s1[j] += v;
            s2[j] += v * v;
            o[j] = (_Float16)v;
        }
        *(h8v*)(A + (size_t)Rr * HH + c8) = o;
    }
#pragma unroll
    for (int j = 0; j < 8; j++) { L1[t][j] = s1[j]; L2[t][j] = s2[j]; }
    __syncthreads();
    if (t < 16) {
#pragma unroll
        for (int g = 1; g < 16; g++)
#pragma unroll
            for (int j = 0; j < 8; j++) {
                s1[j] = (g == 1 ? L1[t][j] : s1[j]) + L1[t + 16 * g][j];
                s2[j] = (g == 1 ? L2[t][j] : s2[j]) + L2[t + 16 * g][j];
            }
#pragma unroll
        for (int j = 0; j < 8; j++) {
            pS1[(size_t)(t * 8 + j) * NPART0 + blockIdx.x] = s1[j];
            pS2[(size_t)(t * 8 + j) * NPART0 + blockIdx.x] = s2[j];
        }
    }
}

// ---------------- activation pass: h' = relu(A*sc+sh), f16 -> f16 ----------------
__global__ void __launch_bounds__(256) k_act(const _Float16* __restrict__ A,
                                             _Float16* __restrict__ HP,
                                             const float* __restrict__ scale,
                                             const float* __restrict__ shiftv) {
    int i = blockIdx.x * 256 + threadIdx.x;
    int c8 = (i & 15) * 8;
    h8v v = *(const h8v*)(A + (size_t)i * 8);
    h8v o;
#pragma unroll
    for (int j = 0; j < 8; j++) {
        float f = (float)v[j] * scale[c8 + j] + shiftv[c8 + j];
        o[j] = (_Float16)fmaxf(f, 0.f);
    }
    *(h8v*)(HP + (size_t)i * 8) = o;
}

// ---------------- FUSED: gather (wave-per-node) -> LDS -> 16-row MFMA -> A + stats ----
// 512 thr = 8 waves = 8 nodes = 16 rows; chunk = blockIdx&7 (XCD-routed, L2-resident).
__global__ void __launch_bounds__(512) k_fused(const _Float16* __restrict__ h,
                                               _Float16* __restrict__ A,
                                               const _Float16* __restrict__ Wh,
                                               const float* __restrict__ bias,
                                               const int* __restrict__ rowptr4,
                                               const int2* __restrict__ csr,
                                               const unsigned* __restrict__ d2p, int shn,
                                               float* __restrict__ pS1,
                                               float* __restrict__ pS2) {
    __shared__ _Float16 pt[16 * 128];           // swizzled 16-row tile, 4 KB
    __shared__ float rb1[4][128], rb2[4][128];  // 4 KB stats reduction
    int t = threadIdx.x;
    int q = blockIdx.x & 7;     // chunk -> XCD routing
    int g8 = blockIdx.x >> 3;   // 0..1124
    int wv = t >> 6, l = t & 63;
    int n = g8 * 8 + wv;        // wave's node (1125*8 = 9000 exact)
    int half = l >> 5, li = l & 31;
    const _Float16* hb = h + (size_t)q * CROWS * HH + (size_t)li * 8;
    // ---- gather phase (round-13 proven: paired-edge, 8 edges in flight) ----
    int pn = n + shn;
    if (pn >= NN) pn -= NN;
    h8v acc;
    {
        h8v v = *(const h8v*)(hb + (size_t)pn * 2 * HH);
        acc = v * cf8(half ? 0u : d2p[n]);
    }
    int beg = rowptr4[n], end = rowptr4[n + 1];
    int e = beg;
    for (; e + 8 <= end; e += 8) {
        int4 m0 = *(const int4*)(csr + e);
        int4 m1 = *(const int4*)(csr + e + 2);
        int4 m2 = *(const int4*)(csr + e + 4);
        int4 m3 = *(const int4*)(csr + e + 6);
        int s0 = (half ? m0.z : m0.x) + shn; if (s0 >= NN) s0 -= NN;
        int s1 = (half ? m1.z : m1.x) + shn; if (s1 >= NN) s1 -= NN;
        int s2 = (half ? m2.z : m2.x) + shn; if (s2 >= NN) s2 -= NN;
        int s3 = (half ? m3.z : m3.x) + shn; if (s3 >= NN) s3 -= NN;
        h8v v0 = *(const h8v*)(hb + (size_t)s0 * 2 * HH);
        h8v v1 = *(const h8v*)(hb + (size_t)s1 * 2 * HH);
        h8v v2 = *(const h8v*)(hb + (size_t)s2 * 2 * HH);
        h8v v3 = *(const h8v*)(hb + (size_t)s3 * 2 * HH);
        acc += v0 * cf8((unsigned)(half ? m0.w : m0.y));
        acc += v1 * cf8((unsigned)(half ? m1.w : m1.y));
        acc += v2 * cf8((unsigned)(half ? m2.w : m2.y));
        acc += v3 * cf8((unsigned)(half ? m3.w : m3.y));
    }
    if (e < end) {  // exactly 4 edges remain
        int4 m0 = *(const int4*)(csr + e);
        int4 m1 = *(const int4*)(csr + e + 2);
        int s0 = (half ? m0.z : m0.x) + shn; if (s0 >= NN) s0 -= NN;
        int s1 = (half ? m1.z : m1.x) + shn; if (s1 >= NN) s1 -= NN;
        h8v v0 = *(const h8v*)(hb + (size_t)s0 * 2 * HH);
        h8v v1 = *(const h8v*)(hb + (size_t)s1 * 2 * HH);
        acc += v0 * cf8((unsigned)(half ? m0.w : m0.y));
        acc += v1 * cf8((unsigned)(half ? m1.w : m1.y));
    }
    {   // combine even/odd-edge halves
        int4 ai = __builtin_bit_cast(int4, acc);
        int4 bi4;
        bi4.x = __shfl_xor(ai.x, 32, 64);
        bi4.y = __shfl_xor(ai.y, 32, 64);
        bi4.z = __shfl_xor(ai.z, 32, 64);
        bi4.w = __shfl_xor(ai.w, 32, 64);
        acc += __builtin_bit_cast(h8v, bi4);
    }
    if (half == 0) {  // write node slab into swizzled LDS tile
        int row = wv * 2 + (li >> 4);       // local row 0..15
        int pc = (li & 15) ^ row;           // chunk-of-16B XOR-swizzle
        *(h8v*)(pt + row * 128 + pc * 8) = acc;
    }
    __syncthreads();
    // ---- MFMA phase: wave wv computes cols wv*16..wv*16+15 (16x16x32, K=128) ----
    int lc = l & 15, kg = l >> 4;  // col-in-tile / k-group
    int c = wv * 16 + lc;
    const _Float16* Wc = Wh + (size_t)c * HH;
    f4v acc2 = {0.f, 0.f, 0.f, 0.f};
#pragma unroll
    for (int ks = 0; ks < 4; ks++) {
        int arow = lc;                       // A row = lane&15
        int pc = (ks * 4 + kg) ^ arow;       // swizzled chunk
        h8v a = *(const h8v*)(pt + arow * 128 + pc * 8);
        h8v b = *(const h8v*)(Wc + ks * 32 + kg * 8);
        acc2 = __builtin_amdgcn_mfma_f32_16x16x32_f16(a, b, acc2, 0, 0, 0);
    }
    // ---- epilogue: bias, stats, store f16 ----
    float bv = bias[c];
    float s1a = 0.f, s2a = 0.f;
    size_t gbase = (size_t)q * CROWS + (size_t)g8 * 16;
#pragma unroll
    for (int j = 0; j < 4; j++) {
        int row = kg * 4 + j;  // C/D: row = (lane>>4)*4 + reg
        float v = acc2[j] + bv;
        s1a += v;
        s2a += v * v;
        A[(gbase + row) * HH + c] = (_Float16)v;
    }
    rb1[kg][c] = s1a;
    rb2[kg][c] = s2a;
    __syncthreads();
    if (t < 128) {
        float a1 = rb1[0][t] + rb1[1][t] + rb1[2][t] + rb1[3][t];
        float a2 = rb2[0][t] + rb2[1][t] + rb2[2][t] + rb2[3][t];
        pS1[(size_t)t * NPB + blockIdx.x] = a1;  // transposed: [channel][block]
        pS2[(size_t)t * NPB + blockIdx.x] = a2;
    }
}

// finalize BN affine from transposed partials: one block per channel, coalesced rows
__global__ void __launch_bounds__(256) k_bnfin(const float* __restrict__ pS1,
                                               const float* __restrict__ pS2, int npart,
                                               const float* __restrict__ g,
                                               const float* __restrict__ be,
                                               float* __restrict__ scale,
                                               float* __restrict__ shiftv) {
    __shared__ float R1[256], R2[256];
    int c = blockIdx.x;
    int t = threadIdx.x;
    const float* p1 = pS1 + (size_t)c * npart;
    const float* p2 = pS2 + (size_t)c * npart;
    float s1 = 0.f, s2 = 0.f;
    for (int i = t; i < npart; i += 256) {
        s1 += p1[i];
        s2 += p2[i];
    }
    R1[t] = s1;
    R2[t] = s2;
    __syncthreads();
    for (int d = 128; d > 0; d >>= 1) {
        if (t < d) {
            R1[t] += R1[t + d];
            R2[t] += R2[t + d];
        }
        __syncthreads();
    }
    if (t == 0) {
        float inv = 1.0f / (float)RR;
        float mu = R1[0] * inv;
        float var = R2[0] * inv - mu * mu;
        float sc = g[c] * rsqrtf(var + EPSB);
        scale[c] = sc;
        shiftv[c] = be[c] - mu * sc;
    }
}

// fused BN-affine + ReLU + mean-pool (per head), chunk-routed (blockIdx&7 = chunk)
__global__ void __launch_bounds__(256) k_relu_pool(const _Float16* __restrict__ A,
                                                   const float* __restrict__ scale,
                                                   const float* __restrict__ shiftv,
                                                   float* __restrict__ pooled) {
    __shared__ float L[256][8];
    int t = threadIdx.x;
    int q = blockIdx.x & 7;
    int idx = blockIdx.x >> 3;   // 0..71
    int bi = idx & 1;
    int n0 = (idx >> 1) * 250;   // 36 tiles x 250 nodes
    int b = q * 2 + bi;
    int ng = t >> 4, c8 = (t & 15) * 8;
    float sc[8], sh[8];
#pragma unroll
    for (int j = 0; j < 8; j++) {
        sc[j] = scale[c8 + j];
        sh[j] = shiftv[c8 + j];
    }
    const _Float16* Ab = A + ((size_t)q * CROWS + bi) * HH;
    float acc[8];
#pragma unroll
    for (int j = 0; j < 8; j++) acc[j] = 0.f;
    for (int n = n0 + ng; n < n0 + 250; n += 16) {
        h8v v = *(const h8v*)(Ab + (size_t)n * 2 * HH + c8);
#pragma unroll
        for (int j = 0; j < 8; j++) {
            float f = (float)v[j] * sc[j] + sh[j];
            acc[j] += fmaxf(f, 0.f);
        }
    }
#pragma unroll
    for (int j = 0; j < 8; j++) L[t][j] = acc[j];
    __syncthreads();
    if (ng == 0) {
#pragma unroll
        for (int g = 1; g < 16; g++)
#pragma unroll
            for (int j = 0; j < 8; j++) acc[j] += L[t + 16 * g][j];
#pragma unroll
        for (int j = 0; j < 8; j++) atomicAdd(&pooled[b * HH + t * 8 + j], acc[j]);
    }
}

// all 9 heads: linear + log_softmax
__global__ void __launch_bounds__(192) k_head_all(const float* __restrict__ pooled,
                                                  const float* __restrict__ main_Wf,
                                                  const float* __restrict__ main_bf,
                                                  const float* __restrict__ aux_Wf,
                                                  const float* __restrict__ aux_bf,
                                                  float* __restrict__ out) {
    int hd = blockIdx.x;
    const float* Wf = hd ? aux_Wf + (size_t)(hd - 1) * HH * NCLSS : main_Wf;
    const float* bf = hd ? aux_bf + (hd - 1) * NCLSS : main_bf;
    const float* pl = pooled + (size_t)hd * BB * HH;
    __shared__ float z[BB][NCLSS];
    __shared__ float lse[BB];
    int t = threadIdx.x;
    int b = t / NCLSS, j = t % NCLSS;
    if (t < BB * NCLSS) {
        float acc = bf[j];
        const float invn = 1.0f / NN;
        for (int c = 0; c < HH; c++) acc += pl[b * HH + c] * invn * Wf[c * NCLSS + j];
        z[b][j] = acc;
    }
    __syncthreads();
    if (t < BB) {
        float m = -1e30f;
        for (int j2 = 0; j2 < NCLSS; j2++) m = fmaxf(m, z[t][j2]);
        float s = 0.f;
        for (int j2 = 0; j2 < NCLSS; j2++) s += expf(z[t][j2] - m);
        lse[t] = m + logf(s);
    }
    __syncthreads();
    if (t < BB * NCLSS) {
        float* o = hd ? out + BB * NCLSS + ((size_t)b * 8 + (hd - 1)) * NCLSS + j
                      : out + b * NCLSS + j;
        *o = z[b][j] - lse[b];
    }
}

// ---------------- host ----------------

extern "C" void kernel_launch(void* const* d_in, const int* in_sizes, int n_in, void* d_out,
                              int out_size, void* d_ws, size_t ws_size, hipStream_t stream) {
    const float* x = (const float*)d_in[0];
    const int* ei = (const int*)d_in[1];
    const float* W_in = (const float*)d_in[2];
    const float* b_in = (const float*)d_in[3];
    const float* g_in = (const float*)d_in[4];
    const float* be_in = (const float*)d_in[5];
    const float* shared_W = (const float*)d_in[6];
    const float* shared_b = (const float*)d_in[7];
    const float* shared_g = (const float*)d_in[8];
    const float* shared_be = (const float*)d_in[9];
    const float* main_Wg = (const float*)d_in[10];
    const float* main_bg = (const float*)d_in[11];
    const float* main_g = (const float*)d_in[12];
    const float* main_be = (const float*)d_in[13];
    const float* main_Wf = (const float*)d_in[14];
    const float* main_bf = (const float*)d_in[15];
    const float* aux_Wg = (const float*)d_in[16];
    const float* aux_bg = (const float*)d_in[17];
    const float* aux_g = (const float*)d_in[18];
    const float* aux_be = (const float*)d_in[19];
    const float* aux_Wf = (const float*)d_in[20];
    const float* aux_bf = (const float*)d_in[21];
    float* out = (float*)d_out;

    char* w = (char*)d_ws;
    const size_t BIG = (size_t)RR * HH * 2;
    _Float16* U = (_Float16*)w;  w += BIG;
    _Float16* V = (_Float16*)w;  w += BIG;
    _Float16* HP = (_Float16*)w; w += BIG;
    float* P0 = (float*)w;       w += (size_t)RR * 2 * 4;
    _Float16* Wh = (_Float16*)w; w += (size_t)11 * 16384 * 2;
    int2* csr = (int2*)w;        w += (size_t)102400 * 8;  // padded CSR (<=99000 entries)
    int* counts = (int*)w;       w += NN * 4;
    int* cursor = (int*)w;       w += NN * 4;
    float* dinv = (float*)w;     w += NN * 4;
    unsigned* d2p = (unsigned*)w; w += NN * 4;
    int* rowptr4 = (int*)w;      w += 36016;
    float* pS1 = (float*)w;      w += (size_t)HH * NPB * 4;
    float* pS2 = (float*)w;      w += (size_t)HH * NPB * 4;
    float* pooled = (float*)w;   w += 9 * BB * HH * 4;
    float* tscale = (float*)w;   w += 512;
    float* tshift = (float*)w;   w += 512;
    float* hscale = (float*)w;   w += 512;
    float* hshift = (float*)w;   w += 512;

    hipMemsetAsync(counts, 0, 2 * NN * 4, stream);
    hipMemsetAsync(pooled, 0, 9 * BB * HH * 4, stream);

    k_count<<<(EE + 255) / 256, 256, 0, stream>>>(ei, counts);
    k_dinv<<<(NN + 255) / 256, 256, 0, stream>>>(counts, dinv, d2p);
    k_scan<<<1, 1024, 0, stream>>>(counts, rowptr4);
    k_fill<<<(EE + 255) / 256, 256, 0, stream>>>(ei, rowptr4, cursor, dinv, csr);
    k_pad<<<(NN + 255) / 256, 256, 0, stream>>>(rowptr4, cursor, csr);
    k_wcvt<<<(11 * 16384 + 255) / 256, 256, 0, stream>>>(shared_W, main_Wg, aux_Wg, Wh);

    // L0
    {
        dim3 g((NN + 255) / 256, BB);
        k_prop2<<<g, 256, 0, stream>>>(x, P0, rowptr4, csr, dinv);
        k_mm2<<<NPART0, 256, 0, stream>>>(P0, U, W_in, b_in, pS1, pS2);
        k_bnfin<<<HH, 256, 0, stream>>>(pS1, pS2, NPART0, g_in, be_in, tscale, tshift);
    }

    // shared trunk layers: act -> fused(gather+mfma) -> bnfin
    _Float16* hcur = U;
    _Float16* hnext = V;
    for (int l = 0; l < 2; l++) {
        k_act<<<RR * 16 / 256, 256, 0, stream>>>(hcur, HP, tscale, tshift);
        k_fused<<<NPB, 512, 0, stream>>>(HP, hnext, Wh + (size_t)l * 16384, shared_b + l * HH,
                                         rowptr4, csr, d2p, 0, pS1, pS2);
        k_bnfin<<<HH, 256, 0, stream>>>(pS1, pS2, NPB, shared_g + l * HH, shared_be + l * HH,
                                        tscale, tshift);
        _Float16* tmp = hcur; hcur = hnext; hnext = tmp;
    }

    // activate trunk output once; all 9 heads share it
    k_act<<<RR * 16 / 256, 256, 0, stream>>>(hcur, HP, tscale, tshift);

    // heads
    for (int hd = 0; hd < 9; hd++) {
        int shift = hd * 1000;
        const _Float16* Wg = Wh + (size_t)(2 + hd) * 16384;
        const float* bg = (hd == 0) ? main_bg : aux_bg + (hd - 1) * HH;
        const float* gg = (hd == 0) ? main_g : aux_g + (hd - 1) * HH;
        const float* be = (hd == 0) ? main_be : aux_be + (hd - 1) * HH;

        k_fused<<<NPB, 512, 0, stream>>>(HP, hnext, Wg, bg, rowptr4, csr, d2p, shift, pS1, pS2);
        k_bnfin<<<HH, 256, 0, stream>>>(pS1, pS2, NPB, gg, be, hscale, hshift);
        k_relu_pool<<<576, 256, 0, stream>>>(hnext, hscale, hshift,
                                             pooled + (size_t)hd * BB * HH);
    }
    k_head_all<<<9, 192, 0, stream>>>(pooled, main_Wf, main_bf, aux_Wf, aux_bf, out);
}

// Round 15
// 1034.891 us; speedup vs baseline: 1.1830x; 1.1830x over previous
//
#include <hip/hip_runtime.h>
#include <hip/hip_bf16.h>
#include <math.h>

#define BB 16
#define TT 360
#define VV 25
#define NN 9000
#define EE 72000
#define HH 128
#define RR (NN * BB)       // 144000 rows total
#define CROWS 18000        // rows per chunk (9000 nodes x 2 batches)
#define NTILES (RR / 64)   // 2250 tiles of 64 rows for k_mfma2 (exact)
#define NPART0 563         // partial-stats blocks for k_mm2 (L0)
#define NCLSS 12
#define EPSB 1e-5f

// chunked activation layout: row R(n,b) = (b>>1)*CROWS + n*2 + (b&1)

typedef _Float16 h4v __attribute__((ext_vector_type(4)));
typedef _Float16 h8v __attribute__((ext_vector_type(8)));
typedef float float16v __attribute__((ext_vector_type(16)));

__device__ __forceinline__ h8v cf8(unsigned packed) {
    uint4 cc = {packed, packed, packed, packed};
    return __builtin_bit_cast(h8v, cc);
}

// ---------------- graph preprocessing ----------------

__global__ void k_count(const int* __restrict__ ei, int* __restrict__ counts) {
    int e = blockIdx.x * 256 + threadIdx.x;
    if (e < EE) atomicAdd(&counts[ei[EE + e]], 1);
}

__global__ void k_dinv(const int* __restrict__ counts, float* __restrict__ dinv,
                       unsigned* __restrict__ d2p) {
    int n = blockIdx.x * 256 + threadIdx.x;
    if (n >= NN) return;
    float di = rsqrtf((float)(counts[n] + 1));
    dinv[n] = di;
    _Float16 d2 = (_Float16)(di * di);
    unsigned short u = __builtin_bit_cast(unsigned short, d2);
    d2p[n] = (unsigned)u | ((unsigned)u << 16);
}

// exclusive prefix over padded degrees deg4 = (deg+3)&~3
__global__ void k_scan(const int* __restrict__ counts, int* __restrict__ rowptr4) {
    __shared__ int part[1024];
    int t = threadIdx.x;
    int base = t * 9;
    int loc[9];
    int s = 0;
#pragma unroll
    for (int i = 0; i < 9; i++) {
        int idx = base + i;
        int v = (idx < NN) ? ((counts[idx] + 3) & ~3) : 0;
        loc[i] = s;
        s += v;
    }
    part[t] = s;
    __syncthreads();
    for (int d = 1; d < 1024; d <<= 1) {
        int v = (t >= d) ? part[t - d] : 0;
        __syncthreads();
        part[t] += v;
        __syncthreads();
    }
    int excl = (t == 0) ? 0 : part[t - 1];
#pragma unroll
    for (int i = 0; i < 9; i++) {
        int idx = base + i;
        if (idx < NN) rowptr4[idx] = excl + loc[i];
    }
    if (t == 1023) rowptr4[NN] = part[1023];
}

// csr entry: {src, coef packed as half2(cf,cf)}
__global__ void k_fill(const int* __restrict__ ei, const int* __restrict__ rowptr4,
                       int* __restrict__ cursor, const float* __restrict__ dinv,
                       int2* __restrict__ csr) {
    int e = blockIdx.x * 256 + threadIdx.x;
    if (e >= EE) return;
    int s = ei[e], d = ei[EE + e];
    int slot = rowptr4[d] + atomicAdd(&cursor[d], 1);
    _Float16 cfh = (_Float16)(dinv[s] * dinv[d]);
    unsigned short u = __builtin_bit_cast(unsigned short, cfh);
    int2 e2;
    e2.x = s;
    e2.y = (int)((unsigned)u | ((unsigned)u << 16));
    csr[slot] = e2;
}

// fill pad slots with {n, 0} (self row, zero coef)
__global__ void k_pad(const int* __restrict__ rowptr4, const int* __restrict__ cursor,
                      int2* __restrict__ csr) {
    int n = blockIdx.x * 256 + threadIdx.x;
    if (n >= NN) return;
    int beg = rowptr4[n] + cursor[n];
    int end = rowptr4[n + 1];
    int2 z;
    z.x = n;
    z.y = 0;
    for (int e = beg; e < end; e++) csr[e] = z;
}

// pre-convert the 11 layer weight matrices to f16 W^T images: Wh[l][c*128+k]
__global__ void k_wcvt(const float* __restrict__ sW, const float* __restrict__ mW,
                       const float* __restrict__ aW, _Float16* __restrict__ Wh) {
    int idx = blockIdx.x * 256 + threadIdx.x;
    if (idx >= 11 * 16384) return;
    int l = idx >> 14, r = idx & 16383;
    int k = r >> 7, c = r & 127;
    const float* src = (l < 2) ? sW + (size_t)l * 16384
                               : ((l == 2) ? mW : aW + (size_t)(l - 3) * 16384);
    Wh[(size_t)l * 16384 + c * 128 + k] = (_Float16)src[k * 128 + c];
}

// ---------------- L0 propagation of raw x (2 channels, f32) ----------------
__global__ void k_prop2(const float* __restrict__ x, float* __restrict__ P0,
                        const int* __restrict__ rowptr4, const int2* __restrict__ csr,
                        const float* __restrict__ dinv) {
    int n = blockIdx.x * 256 + threadIdx.x;
    if (n >= NN) return;
    int b = blockIdx.y;
    const float* xb = x + (size_t)b * NN * 2;
    float d2 = dinv[n] * dinv[n];
    float a0 = d2 * xb[2 * n], a1 = d2 * xb[2 * n + 1];
    int beg = rowptr4[n], end = rowptr4[n + 1];
    for (int j = beg; j < end; j++) {
        int2 e2 = csr[j];
        int s = e2.x;
        unsigned short u = (unsigned short)((unsigned)e2.y & 0xffffu);
        float cf = (float)__builtin_bit_cast(_Float16, u);
        a0 += cf * xb[2 * s];
        a1 += cf * xb[2 * s + 1];
    }
    float* Pb = P0 + (size_t)(n * BB + b) * 2;
    Pb[0] = a0;
    Pb[1] = a1;
}

// L0 matmul (K=2), writes chunked f16 layout, fused BN partial stats pS[c][part].
__global__ void __launch_bounds__(256) k_mm2(const float* __restrict__ P0,
                                             _Float16* __restrict__ A,
                                             const float* __restrict__ W,
                                             const float* __restrict__ bias,
                                             float* __restrict__ pS1, float* __restrict__ pS2) {
    __shared__ float L1[256][8], L2[256][8];
    int t = threadIdx.x;
    int cg = t & 15, c8 = cg * 8;
    float wv0[8], wv1[8], bv[8];
#pragma unroll
    for (int j = 0; j < 8; j++) {
        wv0[j] = W[c8 + j];
        wv1[j] = W[HH + c8 + j];
        bv[j] = bias[c8 + j];
    }
    float s1[8], s2[8];
#pragma unroll
    for (int j = 0; j < 8; j++) { s1[j] = 0.f; s2[j] = 0.f; }
    for (int idx = blockIdx.x * 256 + t; idx < RR * 16; idx += gridDim.x * 256) {
        int Rr = idx >> 4;
        int q = Rr / CROWS;
        int rr = Rr - q * CROWS;
        int n = rr >> 1;
        int b = q * 2 + (rr & 1);
        float p0 = P0[((size_t)n * BB + b) * 2], p1 = P0[((size_t)n * BB + b) * 2 + 1];
        h8v o;
#pragma unroll
        for (int j = 0; j < 8; j++) {
            float v = p0 * wv0[j] + p1 * wv1[j] + bv[j];
            s1[j] += v;
            s2[j] += v * v;
            o[j] = (_Float16)v;
        }
        *(h8v*)(A + (size_t)Rr * HH + c8) = o;
    }
#pragma unroll
    for (int j = 0; j < 8; j++) { L1[t][j] = s1[j]; L2[t][j] = s2[j]; }
    __syncthreads();
    if (t < 16) {
#pragma unroll
        for (int g = 1; g < 16; g++)
#pragma unroll
            for (int j = 0; j < 8; j++) {
                s1[j] = (g == 1 ? L1[t][j] : s1[j]) + L1[t + 16 * g][j];
                s2[j] = (g == 1 ? L2[t][j] : s2[j]) + L2[t + 16 * g][j];
            }
#pragma unroll
        for (int j = 0; j < 8; j++) {
            pS1[(size_t)(t * 8 + j) * NPART0 + blockIdx.x] = s1[j];
            pS2[(size_t)(t * 8 + j) * NPART0 + blockIdx.x] = s2[j];
        }
    }
}

// ---------------- activation pass: h' = relu(A*sc+sh), f16 -> f16 ----------------
__global__ void __launch_bounds__(256) k_act(const _Float16* __restrict__ A,
                                             _Float16* __restrict__ HP,
                                             const float* __restrict__ scale,
                                             const float* __restrict__ shiftv) {
    int i = blockIdx.x * 256 + threadIdx.x;
    int c8 = (i & 15) * 8;
    h8v v = *(const h8v*)(A + (size_t)i * 8);
    h8v o;
#pragma unroll
    for (int j = 0; j < 8; j++) {
        float f = (float)v[j] * scale[c8 + j] + shiftv[c8 + j];
        o[j] = (_Float16)fmaxf(f, 0.f);
    }
    *(h8v*)(HP + (size_t)i * 8) = o;
}

// ---------------- pure gather: P = A_hat * h', DUAL-node-per-wave, paired-edge ----
// chunked (2 batches = 4.6MB L2-resident, blockIdx&7 XCD-routed).
// wave handles nodes nA=ng*8+wv*2 and nA+1: two independent load chains in flight.
__global__ void __launch_bounds__(256) k_gather(const _Float16* __restrict__ h,
                                                _Float16* __restrict__ P,
                                                const int* __restrict__ rowptr4,
                                                const int2* __restrict__ csr,
                                                const unsigned* __restrict__ d2p, int shn) {
    int t = threadIdx.x;
    int q = blockIdx.x & 7;     // chunk -> XCD routing
    int ng = blockIdx.x >> 3;   // 0..1124
    int wv = t >> 6, l = t & 63;
    int nA = ng * 8 + wv * 2;   // 1125*8 = 9000 exact
    int nB = nA + 1;
    int half = l >> 5, li = l & 31;
    const _Float16* hb = h + (size_t)q * CROWS * HH + (size_t)li * 8;
    int pnA = nA + shn; if (pnA >= NN) pnA -= NN;
    int pnB = nB + shn; if (pnB >= NN) pnB -= NN;
    h8v accA, accB;
    {
        h8v vA = *(const h8v*)(hb + (size_t)pnA * 2 * HH);
        h8v vB = *(const h8v*)(hb + (size_t)pnB * 2 * HH);
        accA = vA * cf8(half ? 0u : d2p[nA]);
        accB = vB * cf8(half ? 0u : d2p[nB]);
    }
    int eA = rowptr4[nA];
    int endA = rowptr4[nA + 1];
    int eB = endA;              // rowptr4[nB] == endA (contiguous)
    int endB = rowptr4[nB + 1];
    while (eA < endA || eB < endB) {
        bool dA = eA < endA, dB = eB < endB;
        int4 mA0, mA1, mB0, mB1;
        h8v vA0, vA1, vB0, vB1;
        if (dA) {
            mA0 = *(const int4*)(csr + eA);
            mA1 = *(const int4*)(csr + eA + 2);
        }
        if (dB) {
            mB0 = *(const int4*)(csr + eB);
            mB1 = *(const int4*)(csr + eB + 2);
        }
        if (dA) {
            int s0 = (half ? mA0.z : mA0.x) + shn; if (s0 >= NN) s0 -= NN;
            int s1 = (half ? mA1.z : mA1.x) + shn; if (s1 >= NN) s1 -= NN;
            vA0 = *(const h8v*)(hb + (size_t)s0 * 2 * HH);
            vA1 = *(const h8v*)(hb + (size_t)s1 * 2 * HH);
        }
        if (dB) {
            int s0 = (half ? mB0.z : mB0.x) + shn; if (s0 >= NN) s0 -= NN;
            int s1 = (half ? mB1.z : mB1.x) + shn; if (s1 >= NN) s1 -= NN;
            vB0 = *(const h8v*)(hb + (size_t)s0 * 2 * HH);
            vB1 = *(const h8v*)(hb + (size_t)s1 * 2 * HH);
        }
        if (dA) {
            accA += vA0 * cf8((unsigned)(half ? mA0.w : mA0.y));
            accA += vA1 * cf8((unsigned)(half ? mA1.w : mA1.y));
            eA += 4;
        }
        if (dB) {
            accB += vB0 * cf8((unsigned)(half ? mB0.w : mB0.y));
            accB += vB1 * cf8((unsigned)(half ? mB1.w : mB1.y));
            eB += 4;
        }
    }
    // combine even/odd-edge halves for both nodes
    {
        int4 ai = __builtin_bit_cast(int4, accA);
        int4 bi4;
        bi4.x = __shfl_xor(ai.x, 32, 64);
        bi4.y = __shfl_xor(ai.y, 32, 64);
        bi4.z = __shfl_xor(ai.z, 32, 64);
        bi4.w = __shfl_xor(ai.w, 32, 64);
        accA += __builtin_bit_cast(h8v, bi4);
        int4 ci = __builtin_bit_cast(int4, accB);
        int4 di4;
        di4.x = __shfl_xor(ci.x, 32, 64);
        di4.y = __shfl_xor(ci.y, 32, 64);
        di4.z = __shfl_xor(ci.z, 32, 64);
        di4.w = __shfl_xor(ci.w, 32, 64);
        accB += __builtin_bit_cast(h8v, di4);
    }
    if (half == 0) {
        _Float16* Pb = P + (size_t)q * CROWS * HH + (size_t)li * 8;
        *(h8v*)(Pb + (size_t)nA * 2 * HH) = accA;
        *(h8v*)(Pb + (size_t)nB * 2 * HH) = accB;
    }
}

// ---------------- dense MFMA matmul (f16): A = P*W + bias, fused BN partial stats ----
__global__ void __launch_bounds__(256) k_mfma2(const _Float16* __restrict__ P,
                                               _Float16* __restrict__ A,
                                               const _Float16* __restrict__ Wh,
                                               const float* __restrict__ bias,
                                               float* __restrict__ pS1,
                                               float* __restrict__ pS2) {
    __shared__ float rb1[4][128], rb2[4][128];  // 4 KB stats reduction
    int t = threadIdx.x;
    int w = t >> 6, l = t & 63;
    int rw = w >> 1, cw = w & 1;  // 32-row half x 64-col half
    int lr = l & 31, hi = l >> 5;
    size_t rbase = (size_t)blockIdx.x * 64;
    const _Float16* Pr0 = P + (rbase + rw * 32 + lr) * HH;
    const _Float16* Wc0 = Wh + (size_t)(cw * 64 + lr) * HH;
    const _Float16* Wc1 = Wh + (size_t)(cw * 64 + 32 + lr) * HH;
    float16v acc2[2];
#pragma unroll
    for (int ct = 0; ct < 2; ct++) acc2[ct] = (float16v)(0.0f);
#pragma unroll
    for (int ks = 0; ks < 8; ks++) {
        int koff = ks * 16 + hi * 8;
        h8v a0 = *(const h8v*)(Pr0 + koff);
        h8v b0 = *(const h8v*)(Wc0 + koff);
        h8v b1 = *(const h8v*)(Wc1 + koff);
        acc2[0] = __builtin_amdgcn_mfma_f32_32x32x16_f16(a0, b0, acc2[0], 0, 0, 0);
        acc2[1] = __builtin_amdgcn_mfma_f32_32x32x16_f16(a0, b1, acc2[1], 0, 0, 0);
    }
    // epilogue: bias, stats, store f16
    float bv[2] = {bias[cw * 64 + lr], bias[cw * 64 + 32 + lr]};
    float s1a[2] = {0.f, 0.f}, s2a[2] = {0.f, 0.f};
#pragma unroll
    for (int ct = 0; ct < 2; ct++) {
        int c = cw * 64 + ct * 32 + lr;
#pragma unroll
        for (int g = 0; g < 16; g++) {
            int row = rw * 32 + (g & 3) + 8 * (g >> 2) + 4 * hi;
            float v = acc2[ct][g] + bv[ct];
            s1a[ct] += v;
            s2a[ct] += v * v;
            A[(rbase + row) * HH + c] = (_Float16)v;
        }
    }
    int slot = rw * 2 + hi;
#pragma unroll
    for (int ct = 0; ct < 2; ct++) {
        int cidx = cw * 64 + ct * 32 + lr;
        rb1[slot][cidx] = s1a[ct];
        rb2[slot][cidx] = s2a[ct];
    }
    __syncthreads();
    if (t < 128) {
        float a1 = rb1[0][t] + rb1[1][t] + rb1[2][t] + rb1[3][t];
        float a2 = rb2[0][t] + rb2[1][t] + rb2[2][t] + rb2[3][t];
        pS1[(size_t)t * NTILES + blockIdx.x] = a1;  // transposed: [channel][tile]
        pS2[(size_t)t * NTILES + blockIdx.x] = a2;
    }
}

// finalize BN affine from transposed partials: one block per channel, coalesced rows
__global__ void __launch_bounds__(256) k_bnfin(const float* __restrict__ pS1,
                                               const float* __restrict__ pS2, int npart,
                                               const float* __restrict__ g,
                                               const float* __restrict__ be,
                                               float* __restrict__ scale,
                                               float* __restrict__ shiftv) {
    __shared__ float R1[256], R2[256];
    int c = blockIdx.x;
    int t = threadIdx.x;
    const float* p1 = pS1 + (size_t)c * npart;
    const float* p2 = pS2 + (size_t)c * npart;
    float s1 = 0.f, s2 = 0.f;
    for (int i = t; i < npart; i += 256) {
        s1 += p1[i];
        s2 += p2[i];
    }
    R1[t] = s1;
    R2[t] = s2;
    __syncthreads();
    for (int d = 128; d > 0; d >>= 1) {
        if (t < d) {
            R1[t] += R1[t + d];
            R2[t] += R2[t + d];
        }
        __syncthreads();
    }
    if (t == 0) {
        float inv = 1.0f / (float)RR;
        float mu = R1[0] * inv;
        float var = R2[0] * inv - mu * mu;
        float sc = g[c] * rsqrtf(var + EPSB);
        scale[c] = sc;
        shiftv[c] = be[c] - mu * sc;
    }
}

// fused BN-affine + ReLU + mean-pool (per head), chunked f16 reads
__global__ void __launch_bounds__(256) k_relu_pool(const _Float16* __restrict__ A,
                                                   const float* __restrict__ scale,
                                                   const float* __restrict__ shiftv,
                                                   float* __restrict__ pooled) {
    __shared__ float L[256][8];
    int t = threadIdx.x;
    int b = blockIdx.y;
    int n0 = blockIdx.x * 250;
    int ng = t >> 4, c8 = (t & 15) * 8;
    float sc[8], sh[8];
#pragma unroll
    for (int j = 0; j < 8; j++) {
        sc[j] = scale[c8 + j];
        sh[j] = shiftv[c8 + j];
    }
    const _Float16* Ab = A + ((size_t)(b >> 1) * CROWS + (b & 1)) * HH;
    float acc[8];
#pragma unroll
    for (int j = 0; j < 8; j++) acc[j] = 0.f;
    for (int n = n0 + ng; n < n0 + 250; n += 16) {
        h8v v = *(const h8v*)(Ab + (size_t)n * 2 * HH + c8);
#pragma unroll
        for (int j = 0; j < 8; j++) {
            float f = (float)v[j] * sc[j] + sh[j];
            acc[j] += fmaxf(f, 0.f);
        }
    }
#pragma unroll
    for (int j = 0; j < 8; j++) L[t][j] = acc[j];
    __syncthreads();
    if (ng == 0) {
#pragma unroll
        for (int g = 1; g < 16; g++)
#pragma unroll
            for (int j = 0; j < 8; j++) acc[j] += L[t + 16 * g][j];
#pragma unroll
        for (int j = 0; j < 8; j++) atomicAdd(&pooled[b * HH + t * 8 + j], acc[j]);
    }
}

// all 9 heads: linear + log_softmax
__global__ void __launch_bounds__(192) k_head_all(const float* __restrict__ pooled,
                                                  const float* __restrict__ main_Wf,
                                                  const float* __restrict__ main_bf,
                                                  const float* __restrict__ aux_Wf,
                                                  const float* __restrict__ aux_bf,
                                                  float* __restrict__ out) {
    int hd = blockIdx.x;
    const float* Wf = hd ? aux_Wf + (size_t)(hd - 1) * HH * NCLSS : main_Wf;
    const float* bf = hd ? aux_bf + (hd - 1) * NCLSS : main_bf;
    const float* pl = pooled + (size_t)hd * BB * HH;
    __shared__ float z[BB][NCLSS];
    __shared__ float lse[BB];
    int t = threadIdx.x;
    int b = t / NCLSS, j = t % NCLSS;
    if (t < BB * NCLSS) {
        float acc = bf[j];
        const float invn = 1.0f / NN;
        for (int c = 0; c < HH; c++) acc += pl[b * HH + c] * invn * Wf[c * NCLSS + j];
        z[b][j] = acc;
    }
    __syncthreads();
    if (t < BB) {
        float m = -1e30f;
        for (int j2 = 0; j2 < NCLSS; j2++) m = fmaxf(m, z[t][j2]);
        float s = 0.f;
        for (int j2 = 0; j2 < NCLSS; j2++) s += expf(z[t][j2] - m);
        lse[t] = m + logf(s);
    }
    __syncthreads();
    if (t < BB * NCLSS) {
        float* o = hd ? out + BB * NCLSS + ((size_t)b * 8 + (hd - 1)) * NCLSS + j
                      : out + b * NCLSS + j;
        *o = z[b][j] - lse[b];
    }
}

// ---------------- host ----------------

extern "C" void kernel_launch(void* const* d_in, const int* in_sizes, int n_in, void* d_out,
                              int out_size, void* d_ws, size_t ws_size, hipStream_t stream) {
    const float* x = (const float*)d_in[0];
    const int* ei = (const int*)d_in[1];
    const float* W_in = (const float*)d_in[2];
    const float* b_in = (const float*)d_in[3];
    const float* g_in = (const float*)d_in[4];
    const float* be_in = (const float*)d_in[5];
    const float* shared_W = (const float*)d_in[6];
    const float* shared_b = (const float*)d_in[7];
    const float* shared_g = (const float*)d_in[8];
    const float* shared_be = (const float*)d_in[9];
    const float* main_Wg = (const float*)d_in[10];
    const float* main_bg = (const float*)d_in[11];
    const float* main_g = (const float*)d_in[12];
    const float* main_be = (const float*)d_in[13];
    const float* main_Wf = (const float*)d_in[14];
    const float* main_bf = (const float*)d_in[15];
    const float* aux_Wg = (const float*)d_in[16];
    const float* aux_bg = (const float*)d_in[17];
    const float* aux_g = (const float*)d_in[18];
    const float* aux_be = (const float*)d_in[19];
    const float* aux_Wf = (const float*)d_in[20];
    const float* aux_bf = (const float*)d_in[21];
    float* out = (float*)d_out;

    char* w = (char*)d_ws;
    const size_t BIG = (size_t)RR * HH * 2;
    _Float16* U = (_Float16*)w;  w += BIG;
    _Float16* V = (_Float16*)w;  w += BIG;
    _Float16* P = (_Float16*)w;  w += BIG;
    _Float16* HP = (_Float16*)w; w += BIG;
    float* P0 = (float*)w;       w += (size_t)RR * 2 * 4;
    _Float16* Wh = (_Float16*)w; w += (size_t)11 * 16384 * 2;
    int2* csr = (int2*)w;        w += (size_t)102400 * 8;  // padded CSR (<=99000 entries)
    int* counts = (int*)w;       w += NN * 4;
    int* cursor = (int*)w;       w += NN * 4;
    float* dinv = (float*)w;     w += NN * 4;
    unsigned* d2p = (unsigned*)w; w += NN * 4;
    int* rowptr4 = (int*)w;      w += 36016;
    float* pS1 = (float*)w;      w += (size_t)HH * NTILES * 4;
    float* pS2 = (float*)w;      w += (size_t)HH * NTILES * 4;
    float* pooled = (float*)w;   w += 9 * BB * HH * 4;
    float* tscale = (float*)w;   w += 512;
    float* tshift = (float*)w;   w += 512;
    float* hscale = (float*)w;   w += 512;
    float* hshift = (float*)w;   w += 512;

    hipMemsetAsync(counts, 0, 2 * NN * 4, stream);
    hipMemsetAsync(pooled, 0, 9 * BB * HH * 4, stream);

    k_count<<<(EE + 255) / 256, 256, 0, stream>>>(ei, counts);
    k_dinv<<<(NN + 255) / 256, 256, 0, stream>>>(counts, dinv, d2p);
    k_scan<<<1, 1024, 0, stream>>>(counts, rowptr4);
    k_fill<<<(EE + 255) / 256, 256, 0, stream>>>(ei, rowptr4, cursor, dinv, csr);
    k_pad<<<(NN + 255) / 256, 256, 0, stream>>>(rowptr4, cursor, csr);
    k_wcvt<<<(11 * 16384 + 255) / 256, 256, 0, stream>>>(shared_W, main_Wg, aux_Wg, Wh);

    // L0
    {
        dim3 g((NN + 255) / 256, BB);
        k_prop2<<<g, 256, 0, stream>>>(x, P0, rowptr4, csr, dinv);
        k_mm2<<<NPART0, 256, 0, stream>>>(P0, U, W_in, b_in, pS1, pS2);
        k_bnfin<<<HH, 256, 0, stream>>>(pS1, pS2, NPART0, g_in, be_in, tscale, tshift);
    }

    // shared trunk layers: act -> gather -> mfma -> bnfin
    _Float16* hcur = U;
    _Float16* hnext = V;
    for (int l = 0; l < 2; l++) {
        k_act<<<RR * 16 / 256, 256, 0, stream>>>(hcur, HP, tscale, tshift);
        k_gather<<<8 * 1125, 256, 0, stream>>>(HP, P, rowptr4, csr, d2p, 0);
        k_mfma2<<<NTILES, 256, 0, stream>>>(P, hnext, Wh + (size_t)l * 16384,
                                            shared_b + l * HH, pS1, pS2);
        k_bnfin<<<HH, 256, 0, stream>>>(pS1, pS2, NTILES, shared_g + l * HH, shared_be + l * HH,
                                        tscale, tshift);
        _Float16* tmp = hcur; hcur = hnext; hnext = tmp;
    }

    // activate trunk output once; all 9 heads share it
    k_act<<<RR * 16 / 256, 256, 0, stream>>>(hcur, HP, tscale, tshift);

    // heads
    for (int hd = 0; hd < 9; hd++) {
        int shift = hd * 1000;
        const _Float16* Wg = Wh + (size_t)(2 + hd) * 16384;
        const float* bg = (hd == 0) ? main_bg : aux_bg + (hd - 1) * HH;
        const float* gg = (hd == 0) ? main_g : aux_g + (hd - 1) * HH;
        const float* be = (hd == 0) ? main_be : aux_be + (hd - 1) * HH;

        k_gather<<<8 * 1125, 256, 0, stream>>>(HP, P, rowptr4, csr, d2p, shift);
        k_mfma2<<<NTILES, 256, 0, stream>>>(P, hnext, Wg, bg, pS1, pS2);
        k_bnfin<<<HH, 256, 0, stream>>>(pS1, pS2, NTILES, gg, be, hscale, hshift);
        dim3 gp(36, BB);
        k_relu_pool<<<gp, 256, 0, stream>>>(hnext, hscale, hshift, pooled + (size_t)hd * BB * HH);
    }
    k_head_all<<<9, 192, 0, stream>>>(pooled, main_Wf, main_bf, aux_Wf, aux_bf, out);
}

// Round 16
// 868.213 us; speedup vs baseline: 1.4101x; 1.1920x over previous
//
#include <hip/hip_runtime.h>
#include <hip/hip_bf16.h>
#include <math.h>

#define BB 16
#define TT 360
#define VV 25
#define NN 9000
#define EE 72000
#define HH 128
#define RR (NN * BB)       // 144000 rows total
#define CROWS 18000        // rows per chunk (9000 nodes x 2 batches)
#define NTILES (RR / 64)   // 2250 tiles of 64 rows (exact)
#define NPART0 563         // partial-stats blocks for k_mm2 (L0)
#define NCLSS 12
#define EPSB 1e-5f

// chunked activation layout: row R(n,b) = (b>>1)*CROWS + n*2 + (b&1)

typedef _Float16 h4v __attribute__((ext_vector_type(4)));
typedef _Float16 h8v __attribute__((ext_vector_type(8)));
typedef float float16v __attribute__((ext_vector_type(16)));

__device__ __forceinline__ h8v cf8(unsigned packed) {
    uint4 cc = {packed, packed, packed, packed};
    return __builtin_bit_cast(h8v, cc);
}

// ---------------- graph preprocessing ----------------

__global__ void k_count(const int* __restrict__ ei, int* __restrict__ counts) {
    int e = blockIdx.x * 256 + threadIdx.x;
    if (e < EE) atomicAdd(&counts[ei[EE + e]], 1);
}

__global__ void k_dinv(const int* __restrict__ counts, float* __restrict__ dinv,
                       unsigned* __restrict__ d2p) {
    int n = blockIdx.x * 256 + threadIdx.x;
    if (n >= NN) return;
    float di = rsqrtf((float)(counts[n] + 1));
    dinv[n] = di;
    _Float16 d2 = (_Float16)(di * di);
    unsigned short u = __builtin_bit_cast(unsigned short, d2);
    d2p[n] = (unsigned)u | ((unsigned)u << 16);
}

// exclusive prefix over padded degrees deg4 = (deg+3)&~3
__global__ void k_scan(const int* __restrict__ counts, int* __restrict__ rowptr4) {
    __shared__ int part[1024];
    int t = threadIdx.x;
    int base = t * 9;
    int loc[9];
    int s = 0;
#pragma unroll
    for (int i = 0; i < 9; i++) {
        int idx = base + i;
        int v = (idx < NN) ? ((counts[idx] + 3) & ~3) : 0;
        loc[i] = s;
        s += v;
    }
    part[t] = s;
    __syncthreads();
    for (int d = 1; d < 1024; d <<= 1) {
        int v = (t >= d) ? part[t - d] : 0;
        __syncthreads();
        part[t] += v;
        __syncthreads();
    }
    int excl = (t == 0) ? 0 : part[t - 1];
#pragma unroll
    for (int i = 0; i < 9; i++) {
        int idx = base + i;
        if (idx < NN) rowptr4[idx] = excl + loc[i];
    }
    if (t == 1023) rowptr4[NN] = part[1023];
}

// csr entry: {src, coef packed as half2(cf,cf)}
__global__ void k_fill(const int* __restrict__ ei, const int* __restrict__ rowptr4,
                       int* __restrict__ cursor, const float* __restrict__ dinv,
                       int2* __restrict__ csr) {
    int e = blockIdx.x * 256 + threadIdx.x;
    if (e >= EE) return;
    int s = ei[e], d = ei[EE + e];
    int slot = rowptr4[d] + atomicAdd(&cursor[d], 1);
    _Float16 cfh = (_Float16)(dinv[s] * dinv[d]);
    unsigned short u = __builtin_bit_cast(unsigned short, cfh);
    int2 e2;
    e2.x = s;
    e2.y = (int)((unsigned)u | ((unsigned)u << 16));
    csr[slot] = e2;
}

// fill pad slots with {n, 0}
__global__ void k_pad(const int* __restrict__ rowptr4, const int* __restrict__ cursor,
                      int2* __restrict__ csr) {
    int n = blockIdx.x * 256 + threadIdx.x;
    if (n >= NN) return;
    int beg = rowptr4[n] + cursor[n];
    int end = rowptr4[n + 1];
    int2 z;
    z.x = n;
    z.y = 0;
    for (int e = beg; e < end; e++) csr[e] = z;
}

// pre-convert the 11 layer weight matrices to f16 W^T images: Wh[l][c*128+k]
__global__ void k_wcvt(const float* __restrict__ sW, const float* __restrict__ mW,
                       const float* __restrict__ aW, _Float16* __restrict__ Wh) {
    int idx = blockIdx.x * 256 + threadIdx.x;
    if (idx >= 11 * 16384) return;
    int l = idx >> 14, r = idx & 16383;
    int k = r >> 7, c = r & 127;
    const float* src = (l < 2) ? sW + (size_t)l * 16384
                               : ((l == 2) ? mW : aW + (size_t)(l - 3) * 16384);
    Wh[(size_t)l * 16384 + c * 128 + k] = (_Float16)src[k * 128 + c];
}

// ---------------- L0 propagation of raw x (2 channels, f32) ----------------
__global__ void k_prop2(const float* __restrict__ x, float* __restrict__ P0,
                        const int* __restrict__ rowptr4, const int2* __restrict__ csr,
                        const float* __restrict__ dinv) {
    int n = blockIdx.x * 256 + threadIdx.x;
    if (n >= NN) return;
    int b = blockIdx.y;
    const float* xb = x + (size_t)b * NN * 2;
    float d2 = dinv[n] * dinv[n];
    float a0 = d2 * xb[2 * n], a1 = d2 * xb[2 * n + 1];
    int beg = rowptr4[n], end = rowptr4[n + 1];
    for (int j = beg; j < end; j++) {
        int2 e2 = csr[j];
        int s = e2.x;
        unsigned short u = (unsigned short)((unsigned)e2.y & 0xffffu);
        float cf = (float)__builtin_bit_cast(_Float16, u);
        a0 += cf * xb[2 * s];
        a1 += cf * xb[2 * s + 1];
    }
    float* Pb = P0 + (size_t)(n * BB + b) * 2;
    Pb[0] = a0;
    Pb[1] = a1;
}

// L0 matmul (K=2), writes chunked f16 layout, fused BN partial stats pS[c][part].
__global__ void __launch_bounds__(256) k_mm2(const float* __restrict__ P0,
                                             _Float16* __restrict__ A,
                                             const float* __restrict__ W,
                                             const float* __restrict__ bias,
                                             float* __restrict__ pS1, float* __restrict__ pS2) {
    __shared__ float L1[256][8], L2[256][8];
    int t = threadIdx.x;
    int cg = t & 15, c8 = cg * 8;
    float wv0[8], wv1[8], bv[8];
#pragma unroll
    for (int j = 0; j < 8; j++) {
        wv0[j] = W[c8 + j];
        wv1[j] = W[HH + c8 + j];
        bv[j] = bias[c8 + j];
    }
    float s1[8], s2[8];
#pragma unroll
    for (int j = 0; j < 8; j++) { s1[j] = 0.f; s2[j] = 0.f; }
    for (int idx = blockIdx.x * 256 + t; idx < RR * 16; idx += gridDim.x * 256) {
        int Rr = idx >> 4;
        int q = Rr / CROWS;
        int rr = Rr - q * CROWS;
        int n = rr >> 1;
        int b = q * 2 + (rr & 1);
        float p0 = P0[((size_t)n * BB + b) * 2], p1 = P0[((size_t)n * BB + b) * 2 + 1];
        h8v o;
#pragma unroll
        for (int j = 0; j < 8; j++) {
            float v = p0 * wv0[j] + p1 * wv1[j] + bv[j];
            s1[j] += v;
            s2[j] += v * v;
            o[j] = (_Float16)v;
        }
        *(h8v*)(A + (size_t)Rr * HH + c8) = o;
    }
#pragma unroll
    for (int j = 0; j < 8; j++) { L1[t][j] = s1[j]; L2[t][j] = s2[j]; }
    __syncthreads();
    if (t < 16) {
#pragma unroll
        for (int g = 1; g < 16; g++)
#pragma unroll
            for (int j = 0; j < 8; j++) {
                s1[j] = (g == 1 ? L1[t][j] : s1[j]) + L1[t + 16 * g][j];
                s2[j] = (g == 1 ? L2[t][j] : s2[j]) + L2[t + 16 * g][j];
            }
#pragma unroll
        for (int j = 0; j < 8; j++) {
            pS1[(size_t)(t * 8 + j) * NPART0 + blockIdx.x] = s1[j];
            pS2[(size_t)(t * 8 + j) * NPART0 + blockIdx.x] = s2[j];
        }
    }
}

// ---------------- activation pass: h' = relu(A*sc+sh), f16 -> f16 ----------------
__global__ void __launch_bounds__(256) k_act(const _Float16* __restrict__ A,
                                             _Float16* __restrict__ HP,
                                             const float* __restrict__ scale,
                                             const float* __restrict__ shiftv) {
    int i = blockIdx.x * 256 + threadIdx.x;
    int c8 = (i & 15) * 8;
    h8v v = *(const h8v*)(A + (size_t)i * 8);
    h8v o;
#pragma unroll
    for (int j = 0; j < 8; j++) {
        float f = (float)v[j] * scale[c8 + j] + shiftv[c8 + j];
        o[j] = (_Float16)fmaxf(f, 0.f);
    }
    *(h8v*)(HP + (size_t)i * 8) = o;
}

// ---------------- gather x3: P_z = A_hat * shift_z(h'), round-13 proven body ----------------
// grid (8*2250, NZ): z selects dest buffer + shift. Chunked, XCD-routed, paired-edge.
__global__ void __launch_bounds__(256) k_gather3(const _Float16* __restrict__ h,
                                                 _Float16* B0, _Float16* B1, _Float16* B2,
                                                 const int* __restrict__ rowptr4,
                                                 const int2* __restrict__ csr,
                                                 const unsigned* __restrict__ d2p, int shbase) {
    int z = blockIdx.y;
    _Float16* Pz = (z == 0) ? B0 : ((z == 1) ? B1 : B2);
    int shn = shbase + z * 1000;
    int t = threadIdx.x;
    int q = blockIdx.x & 7;     // chunk -> XCD routing
    int ng4 = blockIdx.x >> 3;  // 0..2249
    int wv = t >> 6, l = t & 63;
    int n = ng4 * 4 + wv;       // wave's node (2250*4 = 9000 exact)
    int half = l >> 5, li = l & 31;
    const _Float16* hb = h + (size_t)q * CROWS * HH + (size_t)li * 8;
    int pn = n + shn;
    if (pn >= NN) pn -= NN;
    h8v acc;
    {
        h8v v = *(const h8v*)(hb + (size_t)pn * 2 * HH);
        acc = v * cf8(half ? 0u : d2p[n]);
    }
    int beg = rowptr4[n], end = rowptr4[n + 1];
    int e = beg;
    for (; e + 8 <= end; e += 8) {
        int4 m0 = *(const int4*)(csr + e);
        int4 m1 = *(const int4*)(csr + e + 2);
        int4 m2 = *(const int4*)(csr + e + 4);
        int4 m3 = *(const int4*)(csr + e + 6);
        int s0 = (half ? m0.z : m0.x) + shn; if (s0 >= NN) s0 -= NN;
        int s1 = (half ? m1.z : m1.x) + shn; if (s1 >= NN) s1 -= NN;
        int s2 = (half ? m2.z : m2.x) + shn; if (s2 >= NN) s2 -= NN;
        int s3 = (half ? m3.z : m3.x) + shn; if (s3 >= NN) s3 -= NN;
        h8v v0 = *(const h8v*)(hb + (size_t)s0 * 2 * HH);
        h8v v1 = *(const h8v*)(hb + (size_t)s1 * 2 * HH);
        h8v v2 = *(const h8v*)(hb + (size_t)s2 * 2 * HH);
        h8v v3 = *(const h8v*)(hb + (size_t)s3 * 2 * HH);
        acc += v0 * cf8((unsigned)(half ? m0.w : m0.y));
        acc += v1 * cf8((unsigned)(half ? m1.w : m1.y));
        acc += v2 * cf8((unsigned)(half ? m2.w : m2.y));
        acc += v3 * cf8((unsigned)(half ? m3.w : m3.y));
    }
    if (e < end) {  // exactly 4 edges remain
        int4 m0 = *(const int4*)(csr + e);
        int4 m1 = *(const int4*)(csr + e + 2);
        int s0 = (half ? m0.z : m0.x) + shn; if (s0 >= NN) s0 -= NN;
        int s1 = (half ? m1.z : m1.x) + shn; if (s1 >= NN) s1 -= NN;
        h8v v0 = *(const h8v*)(hb + (size_t)s0 * 2 * HH);
        h8v v1 = *(const h8v*)(hb + (size_t)s1 * 2 * HH);
        acc += v0 * cf8((unsigned)(half ? m0.w : m0.y));
        acc += v1 * cf8((unsigned)(half ? m1.w : m1.y));
    }
    {   // combine even/odd-edge halves
        int4 ai = __builtin_bit_cast(int4, acc);
        int4 bi4;
        bi4.x = __shfl_xor(ai.x, 32, 64);
        bi4.y = __shfl_xor(ai.y, 32, 64);
        bi4.z = __shfl_xor(ai.z, 32, 64);
        bi4.w = __shfl_xor(ai.w, 32, 64);
        acc += __builtin_bit_cast(h8v, bi4);
    }
    if (half == 0) {
        *(h8v*)(Pz + ((size_t)q * CROWS + (size_t)n * 2) * HH + (size_t)li * 8) = acc;
    }
}

// ---------------- MFMA x3, IN-PLACE: B_z = B_z * W_z + bias_z, fused BN stats ----------------
// each 64-row block reads only its own rows; barrier drains reads before overwrite.
__global__ void __launch_bounds__(256) k_mfma3(_Float16* B0, _Float16* B1, _Float16* B2,
                                               const _Float16* __restrict__ Wh_g,
                                               const float* bias0, const float* bias1,
                                               const float* bias2,
                                               float* __restrict__ pS1,
                                               float* __restrict__ pS2) {
    __shared__ float rb1[4][128], rb2[4][128];
    int z = blockIdx.y;
    _Float16* B = (z == 0) ? B0 : ((z == 1) ? B1 : B2);
    const _Float16* Wh = Wh_g + (size_t)z * 16384;
    const float* bias = (z == 0) ? bias0 : ((z == 1) ? bias1 : bias2);
    int t = threadIdx.x;
    int w = t >> 6, l = t & 63;
    int rw = w >> 1, cw = w & 1;
    int lr = l & 31, hi = l >> 5;
    size_t rbase = (size_t)blockIdx.x * 64;
    const _Float16* Pr0 = B + (rbase + rw * 32 + lr) * HH;
    const _Float16* Wc0 = Wh + (size_t)(cw * 64 + lr) * HH;
    const _Float16* Wc1 = Wh + (size_t)(cw * 64 + 32 + lr) * HH;
    float16v acc2[2];
#pragma unroll
    for (int ct = 0; ct < 2; ct++) acc2[ct] = (float16v)(0.0f);
#pragma unroll
    for (int ks = 0; ks < 8; ks++) {
        int koff = ks * 16 + hi * 8;
        h8v a0 = *(const h8v*)(Pr0 + koff);
        h8v b0 = *(const h8v*)(Wc0 + koff);
        h8v b1 = *(const h8v*)(Wc1 + koff);
        acc2[0] = __builtin_amdgcn_mfma_f32_32x32x16_f16(a0, b0, acc2[0], 0, 0, 0);
        acc2[1] = __builtin_amdgcn_mfma_f32_32x32x16_f16(a0, b1, acc2[1], 0, 0, 0);
    }
    __syncthreads();  // drain all waves' reads of this tile before in-place overwrite
    // epilogue: bias, stats, store f16 (in place)
    float bv[2] = {bias[cw * 64 + lr], bias[cw * 64 + 32 + lr]};
    float s1a[2] = {0.f, 0.f}, s2a[2] = {0.f, 0.f};
#pragma unroll
    for (int ct = 0; ct < 2; ct++) {
        int c = cw * 64 + ct * 32 + lr;
#pragma unroll
        for (int g = 0; g < 16; g++) {
            int row = rw * 32 + (g & 3) + 8 * (g >> 2) + 4 * hi;
            float v = acc2[ct][g] + bv[ct];
            s1a[ct] += v;
            s2a[ct] += v * v;
            B[(rbase + row) * HH + c] = (_Float16)v;
        }
    }
    int slot = rw * 2 + hi;
#pragma unroll
    for (int ct = 0; ct < 2; ct++) {
        int cidx = cw * 64 + ct * 32 + lr;
        rb1[slot][cidx] = s1a[ct];
        rb2[slot][cidx] = s2a[ct];
    }
    __syncthreads();
    if (t < 128) {
        float a1 = rb1[0][t] + rb1[1][t] + rb1[2][t] + rb1[3][t];
        float a2 = rb2[0][t] + rb2[1][t] + rb2[2][t] + rb2[3][t];
        pS1[((size_t)z * HH + t) * NTILES + blockIdx.x] = a1;
        pS2[((size_t)z * HH + t) * NTILES + blockIdx.x] = a2;
    }
}

// finalize BN affine from transposed partials, x NZ heads: grid = NZ*128 blocks
__global__ void __launch_bounds__(256) k_bnfin3(const float* __restrict__ pS1,
                                                const float* __restrict__ pS2, int npart,
                                                const float* g0, const float* g1,
                                                const float* g2, const float* be0,
                                                const float* be1, const float* be2,
                                                float* __restrict__ scale,
                                                float* __restrict__ shiftv) {
    __shared__ float R1[256], R2[256];
    int z = blockIdx.x >> 7, c = blockIdx.x & 127;
    const float* g = (z == 0) ? g0 : ((z == 1) ? g1 : g2);
    const float* be = (z == 0) ? be0 : ((z == 1) ? be1 : be2);
    int t = threadIdx.x;
    const float* p1 = pS1 + ((size_t)z * HH + c) * npart;
    const float* p2 = pS2 + ((size_t)z * HH + c) * npart;
    float s1 = 0.f, s2 = 0.f;
    for (int i = t; i < npart; i += 256) {
        s1 += p1[i];
        s2 += p2[i];
    }
    R1[t] = s1;
    R2[t] = s2;
    __syncthreads();
    for (int d = 128; d > 0; d >>= 1) {
        if (t < d) {
            R1[t] += R1[t + d];
            R2[t] += R2[t + d];
        }
        __syncthreads();
    }
    if (t == 0) {
        float inv = 1.0f / (float)RR;
        float mu = R1[0] * inv;
        float var = R2[0] * inv - mu * mu;
        float sc = g[c] * rsqrtf(var + EPSB);
        scale[z * HH + c] = sc;
        shiftv[z * HH + c] = be[c] - mu * sc;
    }
}

// fused BN-affine + ReLU + mean-pool x3 heads: grid (36, BB, 3)
__global__ void __launch_bounds__(256) k_pool3(const _Float16* B0, const _Float16* B1,
                                               const _Float16* B2,
                                               const float* __restrict__ scale,
                                               const float* __restrict__ shiftv,
                                               float* __restrict__ pooled) {
    __shared__ float L[256][8];
    int z = blockIdx.z;
    const _Float16* A = (z == 0) ? B0 : ((z == 1) ? B1 : B2);
    const float* sc0 = scale + z * HH;
    const float* sh0 = shiftv + z * HH;
    float* pz = pooled + (size_t)z * BB * HH;
    int t = threadIdx.x;
    int b = blockIdx.y;
    int n0 = blockIdx.x * 250;
    int ng = t >> 4, c8 = (t & 15) * 8;
    float sc[8], sh[8];
#pragma unroll
    for (int j = 0; j < 8; j++) {
        sc[j] = sc0[c8 + j];
        sh[j] = sh0[c8 + j];
    }
    const _Float16* Ab = A + ((size_t)(b >> 1) * CROWS + (b & 1)) * HH;
    float acc[8];
#pragma unroll
    for (int j = 0; j < 8; j++) acc[j] = 0.f;
    for (int n = n0 + ng; n < n0 + 250; n += 16) {
        h8v v = *(const h8v*)(Ab + (size_t)n * 2 * HH + c8);
#pragma unroll
        for (int j = 0; j < 8; j++) {
            float f = (float)v[j] * sc[j] + sh[j];
            acc[j] += fmaxf(f, 0.f);
        }
    }
#pragma unroll
    for (int j = 0; j < 8; j++) L[t][j] = acc[j];
    __syncthreads();
    if (ng == 0) {
#pragma unroll
        for (int g = 1; g < 16; g++)
#pragma unroll
            for (int j = 0; j < 8; j++) acc[j] += L[t + 16 * g][j];
#pragma unroll
        for (int j = 0; j < 8; j++) atomicAdd(&pz[b * HH + t * 8 + j], acc[j]);
    }
}

// all 9 heads: linear + log_softmax
__global__ void __launch_bounds__(192) k_head_all(const float* __restrict__ pooled,
                                                  const float* __restrict__ main_Wf,
                                                  const float* __restrict__ main_bf,
                                                  const float* __restrict__ aux_Wf,
                                                  const float* __restrict__ aux_bf,
                                                  float* __restrict__ out) {
    int hd = blockIdx.x;
    const float* Wf = hd ? aux_Wf + (size_t)(hd - 1) * HH * NCLSS : main_Wf;
    const float* bf = hd ? aux_bf + (hd - 1) * NCLSS : main_bf;
    const float* pl = pooled + (size_t)hd * BB * HH;
    __shared__ float z[BB][NCLSS];
    __shared__ float lse[BB];
    int t = threadIdx.x;
    int b = t / NCLSS, j = t % NCLSS;
    if (t < BB * NCLSS) {
        float acc = bf[j];
        const float invn = 1.0f / NN;
        for (int c = 0; c < HH; c++) acc += pl[b * HH + c] * invn * Wf[c * NCLSS + j];
        z[b][j] = acc;
    }
    __syncthreads();
    if (t < BB) {
        float m = -1e30f;
        for (int j2 = 0; j2 < NCLSS; j2++) m = fmaxf(m, z[t][j2]);
        float s = 0.f;
        for (int j2 = 0; j2 < NCLSS; j2++) s += expf(z[t][j2] - m);
        lse[t] = m + logf(s);
    }
    __syncthreads();
    if (t < BB * NCLSS) {
        float* o = hd ? out + BB * NCLSS + ((size_t)b * 8 + (hd - 1)) * NCLSS + j
                      : out + b * NCLSS + j;
        *o = z[b][j] - lse[b];
    }
}

// ---------------- host ----------------

extern "C" void kernel_launch(void* const* d_in, const int* in_sizes, int n_in, void* d_out,
                              int out_size, void* d_ws, size_t ws_size, hipStream_t stream) {
    const float* x = (const float*)d_in[0];
    const int* ei = (const int*)d_in[1];
    const float* W_in = (const float*)d_in[2];
    const float* b_in = (const float*)d_in[3];
    const float* g_in = (const float*)d_in[4];
    const float* be_in = (const float*)d_in[5];
    const float* shared_W = (const float*)d_in[6];
    const float* shared_b = (const float*)d_in[7];
    const float* shared_g = (const float*)d_in[8];
    const float* shared_be = (const float*)d_in[9];
    const float* main_Wg = (const float*)d_in[10];
    const float* main_bg = (const float*)d_in[11];
    const float* main_g = (const float*)d_in[12];
    const float* main_be = (const float*)d_in[13];
    const float* main_Wf = (const float*)d_in[14];
    const float* main_bf = (const float*)d_in[15];
    const float* aux_Wg = (const float*)d_in[16];
    const float* aux_bg = (const float*)d_in[17];
    const float* aux_g = (const float*)d_in[18];
    const float* aux_be = (const float*)d_in[19];
    const float* aux_Wf = (const float*)d_in[20];
    const float* aux_bf = (const float*)d_in[21];
    float* out = (float*)d_out;

    char* w = (char*)d_ws;
    const size_t BIG = (size_t)RR * HH * 2;
    _Float16* U = (_Float16*)w;  w += BIG;
    _Float16* V = (_Float16*)w;  w += BIG;
    _Float16* P = (_Float16*)w;  w += BIG;
    _Float16* HP = (_Float16*)w; w += BIG;
    float* P0 = (float*)w;       w += (size_t)RR * 2 * 4;
    _Float16* Wh = (_Float16*)w; w += (size_t)11 * 16384 * 2;
    int2* csr = (int2*)w;        w += (size_t)102400 * 8;  // padded CSR (<=99000 entries)
    int* counts = (int*)w;       w += NN * 4;
    int* cursor = (int*)w;       w += NN * 4;
    float* dinv = (float*)w;     w += NN * 4;
    unsigned* d2p = (unsigned*)w; w += NN * 4;
    int* rowptr4 = (int*)w;      w += 36016;
    float* pS1 = (float*)w;      w += (size_t)3 * HH * NTILES * 4;
    float* pS2 = (float*)w;      w += (size_t)3 * HH * NTILES * 4;
    float* pooled = (float*)w;   w += 9 * BB * HH * 4;
    float* tscale = (float*)w;   w += 512;
    float* tshift = (float*)w;   w += 512;
    float* hscale = (float*)w;   w += 2048;
    float* hshift = (float*)w;   w += 2048;

    hipMemsetAsync(counts, 0, 2 * NN * 4, stream);
    hipMemsetAsync(pooled, 0, 9 * BB * HH * 4, stream);

    k_count<<<(EE + 255) / 256, 256, 0, stream>>>(ei, counts);
    k_dinv<<<(NN + 255) / 256, 256, 0, stream>>>(counts, dinv, d2p);
    k_scan<<<1, 1024, 0, stream>>>(counts, rowptr4);
    k_fill<<<(EE + 255) / 256, 256, 0, stream>>>(ei, rowptr4, cursor, dinv, csr);
    k_pad<<<(NN + 255) / 256, 256, 0, stream>>>(rowptr4, cursor, csr);
    k_wcvt<<<(11 * 16384 + 255) / 256, 256, 0, stream>>>(shared_W, main_Wg, aux_Wg, Wh);

    // L0: prop x, K=2 matmul -> U (pre-BN A0), stats -> tscale/tshift
    {
        dim3 g((NN + 255) / 256, BB);
        k_prop2<<<g, 256, 0, stream>>>(x, P0, rowptr4, csr, dinv);
        k_mm2<<<NPART0, 256, 0, stream>>>(P0, U, W_in, b_in, pS1, pS2);
        k_bnfin3<<<HH, 256, 0, stream>>>(pS1, pS2, NPART0, g_in, g_in, g_in, be_in, be_in,
                                         be_in, tscale, tshift);
    }

    // trunk layer 0: act(U->HP), gather(HP->V), mfma in-place (V), bnfin
    k_act<<<RR * 16 / 256, 256, 0, stream>>>(U, HP, tscale, tshift);
    k_gather3<<<dim3(8 * 2250, 1), 256, 0, stream>>>(HP, V, V, V, rowptr4, csr, d2p, 0);
    k_mfma3<<<dim3(NTILES, 1), 256, 0, stream>>>(V, V, V, Wh, shared_b, shared_b, shared_b,
                                                 pS1, pS2);
    k_bnfin3<<<HH, 256, 0, stream>>>(pS1, pS2, NTILES, shared_g, shared_g, shared_g, shared_be,
                                     shared_be, shared_be, tscale, tshift);
    // trunk layer 1: act(V->HP), gather(HP->U), mfma in-place (U), bnfin
    k_act<<<RR * 16 / 256, 256, 0, stream>>>(V, HP, tscale, tshift);
    k_gather3<<<dim3(8 * 2250, 1), 256, 0, stream>>>(HP, U, U, U, rowptr4, csr, d2p, 0);
    k_mfma3<<<dim3(NTILES, 1), 256, 0, stream>>>(U, U, U, Wh + 16384, shared_b + HH,
                                                 shared_b + HH, shared_b + HH, pS1, pS2);
    k_bnfin3<<<HH, 256, 0, stream>>>(pS1, pS2, NTILES, shared_g + HH, shared_g + HH,
                                     shared_g + HH, shared_be + HH, shared_be + HH,
                                     shared_be + HH, tscale, tshift);
    // trunk output activation (shared by all 9 heads)
    k_act<<<RR * 16 / 256, 256, 0, stream>>>(U, HP, tscale, tshift);

    // heads in 3 groups of 3: {P,U,V} hold the 3 propagations, processed in-place
    for (int g = 0; g < 3; g++) {
        int h0 = g * 3;
        const float* bg[3];
        const float* gg[3];
        const float* be[3];
        for (int z = 0; z < 3; z++) {
            int hd = h0 + z;
            bg[z] = (hd == 0) ? main_bg : aux_bg + (hd - 1) * HH;
            gg[z] = (hd == 0) ? main_g : aux_g + (hd - 1) * HH;
            be[z] = (hd == 0) ? main_be : aux_be + (hd - 1) * HH;
        }
        k_gather3<<<dim3(8 * 2250, 3), 256, 0, stream>>>(HP, P, U, V, rowptr4, csr, d2p,
                                                         h0 * 1000);
        k_mfma3<<<dim3(NTILES, 3), 256, 0, stream>>>(P, U, V, Wh + (size_t)(2 + h0) * 16384,
                                                     bg[0], bg[1], bg[2], pS1, pS2);
        k_bnfin3<<<3 * HH, 256, 0, stream>>>(pS1, pS2, NTILES, gg[0], gg[1], gg[2], be[0],
                                             be[1], be[2], hscale, hshift);
        k_pool3<<<dim3(36, BB, 3), 256, 0, stream>>>(P, U, V, hscale, hshift,
                                                     pooled + (size_t)h0 * BB * HH);
    }
    k_head_all<<<9, 192, 0, stream>>>(pooled, main_Wf, main_bf, aux_Wf, aux_bf, out);
}